// Round 1
// baseline (1016.547 us; speedup 1.0000x reference)
//
#include <hip/hip_runtime.h>
#include <math.h>

#define B_    16
#define C_    384
#define L_    4096
#define K_    4096
#define KH_   32
#define NL_   3
#define HID_  384
#define NFFT  8192
#define NH    4096   // NFFT/2
#define OMEGA_ 976.0f

// ---------------------------------------------------------------------------
// Twiddle table: tw[j] = exp(-2*pi*i*j/NFFT), j = 0..NH-1  (global, L1-cached)
// ---------------------------------------------------------------------------
__global__ __launch_bounds__(256) void gen_tw(float2* __restrict__ tw) {
  int j = blockIdx.x * 256 + threadIdx.x;
  if (j < NH) {
    double a = -2.0 * 3.14159265358979323846 * (double)j / (double)NFFT;
    double s, c;
    sincos(a, &s, &c);
    tw[j] = make_float2((float)c, (float)s);
  }
}

// ---------------------------------------------------------------------------
// Masked MFN kernel generation: mk[c][k] = (h[k]·out_w[c] + out_b[c])*scale*mask[k]
// grid = K_/256 blocks, 256 threads; thread t handles position k = bid*256+t
// ---------------------------------------------------------------------------
__global__ __launch_bounds__(256) void gen_mk(
    const float* __restrict__ mask_mean, const float* __restrict__ mask_sigma,
    const float* __restrict__ gfw, const float* __restrict__ gfb,
    const float* __restrict__ gg,  const float* __restrict__ gmu,
    const float* __restrict__ lin_w, const float* __restrict__ lin_b,
    const float* __restrict__ out_w, const float* __restrict__ out_b,
    float* __restrict__ mk) {
  __shared__ float s_h[256][KH_ + 1];   // h * mask * scale, padded (33) -> conflict-free
  __shared__ float s_ms[256];
  const int t = threadIdx.x;
  const int k = blockIdx.x * 256 + t;
  const float xp = -1.0f + 2.0f * (float)k / (float)(K_ - 1);

  float h[KH_];
  // gabor(0)
  #pragma unroll
  for (int j = 0; j < KH_; ++j) {
    float d   = gg[j] * (xp - gmu[j]);
    float env = expf(-0.5f * d * d);
    float su  = sinf(OMEGA_ * (xp * gfw[j]) + gfb[j]);
    h[j] = env * su;
  }
  // NL hidden layers: h = (h @ lin_w[i].T + lin_b[i]) * gabor(i+1)
  for (int i = 0; i < NL_; ++i) {
    const float* lw = lin_w + i * KH_ * KH_;
    const int go = (i + 1) * KH_;
    float nh[KH_];
    #pragma unroll
    for (int h2 = 0; h2 < KH_; ++h2) {
      float acc = lin_b[i * KH_ + h2];
      #pragma unroll
      for (int j = 0; j < KH_; ++j) acc = fmaf(h[j], lw[h2 * KH_ + j], acc);
      float d   = gg[go + h2] * (xp - gmu[go + h2]);
      float env = expf(-0.5f * d * d);
      float su  = sinf(OMEGA_ * (xp * gfw[go + h2]) + gfb[go + h2]);
      nh[h2] = acc * (env * su);
    }
    #pragma unroll
    for (int j = 0; j < KH_; ++j) h[j] = nh[j];
  }
  // gaussian mask * output re-weight scale
  float mw = (xp - mask_mean[0]) / mask_sigma[0];
  float ms = expf(-0.5f * mw * mw) * rsqrtf((float)(C_ * K_));
  s_ms[t] = ms;
  #pragma unroll
  for (int j = 0; j < KH_; ++j) s_h[t][j] = h[j] * ms;
  __syncthreads();

  // project to C channels; writes coalesced over k
  for (int c = 0; c < C_; ++c) {
    float acc = out_b[c] * s_ms[t];
    #pragma unroll
    for (int j = 0; j < KH_; ++j) acc = fmaf(s_h[t][j], out_w[c * KH_ + j], acc);
    mk[(size_t)c * K_ + k] = acc;
  }
}

// ---------------------------------------------------------------------------
// Radix-2 FFT, N=8192, in LDS (interleaved float2). DIF forward produces
// bit-reversed order; DIT inverse consumes bit-reversed order -> no reversal
// permutation is ever needed (spectra multiplied elementwise in bitrev order).
// ---------------------------------------------------------------------------
__device__ __forceinline__ void fft_dif(float2* z, const float2* __restrict__ tw, int tid) {
  for (int m = NH; m >= 1; m >>= 1) {
    const int stride = NH / m;
    for (int idx = tid; idx < NH; idx += 256) {
      int j = idx & (m - 1);
      int p = ((idx - j) << 1) + j;     // block*2m + j
      float2 a = z[p], b = z[p + m];
      z[p] = make_float2(a.x + b.x, a.y + b.y);
      float trr = a.x - b.x, tii = a.y - b.y;
      float2 w = tw[j * stride];
      z[p + m] = make_float2(trr * w.x - tii * w.y, trr * w.y + tii * w.x);
    }
    __syncthreads();
  }
}

__device__ __forceinline__ void fft_dit_inv(float2* z, const float2* __restrict__ tw, int tid) {
  for (int m = 1; m <= NH; m <<= 1) {
    const int stride = NH / m;
    for (int idx = tid; idx < NH; idx += 256) {
      int j = idx & (m - 1);
      int p = ((idx - j) << 1) + j;
      float2 w = tw[j * stride];        // conjugate for inverse
      float wr = w.x, wi = -w.y;
      float2 b = z[p + m];
      float trr = b.x * wr - b.y * wi;
      float tii = b.x * wi + b.y * wr;
      float2 a = z[p];
      z[p]     = make_float2(a.x + trr, a.y + tii);
      z[p + m] = make_float2(a.x - trr, a.y - tii);
    }
    __syncthreads();
  }
}

// ---------------------------------------------------------------------------
// Kernel spectrum: Hspec[c][j] = FFT(mk[c] zero-padded)[bitrev j] / NFFT
// ---------------------------------------------------------------------------
__global__ __launch_bounds__(256) void fft_h(const float* __restrict__ mk,
                                             const float2* __restrict__ tw,
                                             float2* __restrict__ Hspec) {
  extern __shared__ float2 z[];
  const int c = blockIdx.x;
  const int tid = threadIdx.x;
  const float* row = mk + (size_t)c * K_;
  for (int i = tid; i < K_; i += 256) {
    z[i]      = make_float2(row[i], 0.0f);
    z[i + K_] = make_float2(0.0f, 0.0f);
  }
  __syncthreads();
  fft_dif(z, tw, tid);
  const float inv = 1.0f / (float)NFFT;   // fold IFFT 1/N into kernel spectrum
  float2* outp = Hspec + (size_t)c * NFFT;
  for (int i = tid; i < NFFT; i += 256) {
    float2 v = z[i];
    outp[i] = make_float2(v.x * inv, v.y * inv);
  }
}

// ---------------------------------------------------------------------------
// FFT convolution, two batches per block (two-for-one real FFT):
// z = x[b1] + i*x[b2] (same channel) -> IFFT(FFT(z)*H) = y[b1] + i*y[b2]
// grid = (B_/2)*C_ blocks
// ---------------------------------------------------------------------------
__global__ __launch_bounds__(256) void fft_conv(const float* __restrict__ x,
                                                const float2* __restrict__ Hspec,
                                                const float2* __restrict__ tw,
                                                float* __restrict__ y) {
  extern __shared__ float2 z[];
  const int c  = blockIdx.x % C_;
  const int pr = blockIdx.x / C_;
  const int b1 = 2 * pr, b2 = b1 + 1;
  const int tid = threadIdx.x;
  const float4* x1 = reinterpret_cast<const float4*>(x + ((size_t)b1 * C_ + c) * L_);
  const float4* x2 = reinterpret_cast<const float4*>(x + ((size_t)b2 * C_ + c) * L_);
  for (int i = tid; i < L_ / 4; i += 256) {
    float4 a = x1[i], b = x2[i];
    int p = i * 4;
    z[p]          = make_float2(a.x, b.x);
    z[p + 1]      = make_float2(a.y, b.y);
    z[p + 2]      = make_float2(a.z, b.z);
    z[p + 3]      = make_float2(a.w, b.w);
    z[p + L_]     = make_float2(0.f, 0.f);
    z[p + L_ + 1] = make_float2(0.f, 0.f);
    z[p + L_ + 2] = make_float2(0.f, 0.f);
    z[p + L_ + 3] = make_float2(0.f, 0.f);
  }
  __syncthreads();
  fft_dif(z, tw, tid);
  const float2* H = Hspec + (size_t)c * NFFT;
  for (int i = tid; i < NFFT; i += 256) {
    float2 h = H[i];
    float2 v = z[i];
    z[i] = make_float2(v.x * h.x - v.y * h.y, v.x * h.y + v.y * h.x);
  }
  __syncthreads();
  fft_dit_inv(z, tw, tid);
  float4* y1 = reinterpret_cast<float4*>(y + ((size_t)b1 * C_ + c) * L_);
  float4* y2 = reinterpret_cast<float4*>(y + ((size_t)b2 * C_ + c) * L_);
  for (int i = tid; i < L_ / 4; i += 256) {
    int p = i * 4;
    float2 v0 = z[p], v1 = z[p + 1], v2 = z[p + 2], v3 = z[p + 3];
    y1[i] = make_float4(v0.x, v1.x, v2.x, v3.x);
    y2[i] = make_float4(v0.y, v1.y, v2.y, v3.y);
  }
}

// ---------------------------------------------------------------------------
// Pointwise 1x1 conv: out[b][o][l] = sum_c pw[o][c] * y[b][c][l]
// fp32 tiled GEMM: 64x64 tile, 256 threads, 4x4 acc/thread, BK=16
// grid = (L_/64, HID_/64, B_)
// ---------------------------------------------------------------------------
#define MT 64
#define NT 64
#define KT 16
__global__ __launch_bounds__(256) void pw_gemm(const float* __restrict__ y,
                                               const float* __restrict__ pw,
                                               float* __restrict__ out) {
  const int b  = blockIdx.z;
  const int m0 = blockIdx.y * MT;
  const int n0 = blockIdx.x * NT;
  __shared__ float As[KT][MT + 4];   // [k][m], row stride 68 floats (16B-aligned)
  __shared__ float Bs[KT][NT + 4];   // [k][n]
  const int tid = threadIdx.x;
  const int tx = tid & 15, ty = tid >> 4;
  float acc[4][4] = {{0.f}};
  const float* yb = y + (size_t)b * C_ * L_;

  for (int k0 = 0; k0 < C_; k0 += KT) {
    {  // A tile: pw[m0+r][k0+c4..c4+3], transpose into As[k][m]
      int r = tid >> 2, c4 = (tid & 3) << 2;
      float4 av = *reinterpret_cast<const float4*>(pw + (size_t)(m0 + r) * C_ + k0 + c4);
      As[c4 + 0][r] = av.x; As[c4 + 1][r] = av.y;
      As[c4 + 2][r] = av.z; As[c4 + 3][r] = av.w;
    }
    {  // B tile: y[b][k0+r][n0+cc..cc+3]
      int r = ty, cc = tx << 2;
      float4 bv = *reinterpret_cast<const float4*>(yb + (size_t)(k0 + r) * L_ + n0 + cc);
      *reinterpret_cast<float4*>(&Bs[r][cc]) = bv;
    }
    __syncthreads();
    #pragma unroll
    for (int kk = 0; kk < KT; ++kk) {
      float4 a  = *reinterpret_cast<const float4*>(&As[kk][ty << 2]);
      float4 bv = *reinterpret_cast<const float4*>(&Bs[kk][tx << 2]);
      float av[4] = {a.x, a.y, a.z, a.w};
      float bb[4] = {bv.x, bv.y, bv.z, bv.w};
      #pragma unroll
      for (int i = 0; i < 4; ++i)
        #pragma unroll
        for (int j = 0; j < 4; ++j)
          acc[i][j] = fmaf(av[i], bb[j], acc[i][j]);
    }
    __syncthreads();
  }
  float* ob = out + ((size_t)b * HID_ + m0) * L_ + n0;
  #pragma unroll
  for (int i = 0; i < 4; ++i) {
    float4 v = make_float4(acc[i][0], acc[i][1], acc[i][2], acc[i][3]);
    *reinterpret_cast<float4*>(ob + (size_t)(ty * 4 + i) * L_ + tx * 4) = v;
  }
}

// ---------------------------------------------------------------------------
extern "C" void kernel_launch(void* const* d_in, const int* in_sizes, int n_in,
                              void* d_out, int out_size, void* d_ws, size_t ws_size,
                              hipStream_t stream) {
  (void)in_sizes; (void)n_in; (void)out_size; (void)ws_size;
  const float* x          = (const float*)d_in[0];
  const float* mask_mean  = (const float*)d_in[1];
  const float* mask_sigma = (const float*)d_in[2];
  const float* gfw        = (const float*)d_in[3];
  const float* gfb        = (const float*)d_in[4];
  const float* gg         = (const float*)d_in[5];
  const float* gmu        = (const float*)d_in[6];
  const float* lin_w      = (const float*)d_in[7];
  const float* lin_b      = (const float*)d_in[8];
  const float* out_w      = (const float*)d_in[9];
  const float* out_b      = (const float*)d_in[10];
  const float* pw_w       = (const float*)d_in[11];
  float* out = (float*)d_out;

  // workspace layout (all 16B-aligned):
  //   tw    : float2[NH]            32768 B
  //   mk    : float [C_*K_]      6291456 B
  //   Hspec : float2[C_*NFFT]   25165824 B
  //   y     : float [B_*C_*L_] 100663296 B   (total ~132.2 MB)
  char* ws = (char*)d_ws;
  float2* tw = (float2*)ws;
  float*  mk = (float*)(ws + 32768);
  float2* Hs = (float2*)(ws + 32768 + 6291456);
  float*  y  = (float*)(ws + 32768 + 6291456 + 25165824);

  gen_tw<<<NH / 256, 256, 0, stream>>>(tw);
  gen_mk<<<K_ / 256, 256, 0, stream>>>(mask_mean, mask_sigma, gfw, gfb, gg, gmu,
                                       lin_w, lin_b, out_w, out_b, mk);
  fft_h<<<C_, 256, NFFT * sizeof(float2), stream>>>(mk, tw, Hs);
  fft_conv<<<(B_ / 2) * C_, 256, NFFT * sizeof(float2), stream>>>(x, Hs, tw, y);
  pw_gemm<<<dim3(L_ / 64, HID_ / 64, B_), 256, 0, stream>>>(y, pw_w, out);
}

// Round 2
// 844.713 us; speedup vs baseline: 1.2034x; 1.2034x over previous
//
#include <hip/hip_runtime.h>
#include <math.h>

#define B_    16
#define C_    384
#define L_    4096
#define K_    4096
#define KH_   32
#define NL_   3
#define HID_  384
#define NFFT  8192
#define OMEGA_ 976.0f

// LDS swizzle: XOR bit4 of the float index with bit7 -> all stage strides are
// <=2-way on the 32 banks, and 16-aligned 16-float chunks stay contiguous.
#define SWZ(a) ((a) ^ ((((a) >> 7) & 1) << 4))

// ---------------------------------------------------------------------------
// Twiddles: tw[t] = exp(-2*pi*i*t/NFFT), t = 0..NFFT-1
// ---------------------------------------------------------------------------
__global__ __launch_bounds__(256) void gen_tw(float2* __restrict__ tw) {
  int j = blockIdx.x * 256 + threadIdx.x;
  if (j < NFFT) {
    double a = -2.0 * 3.14159265358979323846 * (double)j / (double)NFFT;
    double s, c;
    sincos(a, &s, &c);
    tw[j] = make_float2((float)c, (float)s);
  }
}

// ------------------------- complex helpers ---------------------------------
__device__ __forceinline__ float2 cadd(float2 a, float2 b) { return make_float2(a.x + b.x, a.y + b.y); }
__device__ __forceinline__ float2 csub(float2 a, float2 b) { return make_float2(a.x - b.x, a.y - b.y); }
__device__ __forceinline__ float2 cmul(float2 a, float2 b) { return make_float2(a.x * b.x - a.y * b.y, a.x * b.y + a.y * b.x); }
__device__ __forceinline__ float2 cmulc(float2 a, float2 b) { // a * conj(b)
  return make_float2(a.x * b.x + a.y * b.y, a.y * b.x - a.x * b.y);
}

// 8-point DFT (forward, W8 = exp(-i*pi/4)), in place
__device__ __forceinline__ void dft8_fwd(float2* a) {
  const float c = 0.70710678118654752f;
  float2 t0 = cadd(a[0], a[4]), t1 = csub(a[0], a[4]);
  float2 t2 = cadd(a[2], a[6]), t3 = csub(a[2], a[6]);
  float2 t4 = cadd(a[1], a[5]), t5 = csub(a[1], a[5]);
  float2 t6 = cadd(a[3], a[7]), t7 = csub(a[3], a[7]);
  float2 E0 = cadd(t0, t2), E2 = csub(t0, t2);
  float2 E1 = make_float2(t1.x + t3.y, t1.y - t3.x);   // t1 - i*t3
  float2 E3 = make_float2(t1.x - t3.y, t1.y + t3.x);   // t1 + i*t3
  float2 O0 = cadd(t4, t6), O2 = csub(t4, t6);
  float2 O1 = make_float2(t5.x + t7.y, t5.y - t7.x);
  float2 O3 = make_float2(t5.x - t7.y, t5.y + t7.x);
  float2 O1w = make_float2(c * (O1.x + O1.y), c * (O1.y - O1.x));   // *W8^1
  float2 O2w = make_float2(O2.y, -O2.x);                            // *W8^2=-i
  float2 O3w = make_float2(c * (O3.y - O3.x), -c * (O3.x + O3.y));  // *W8^3
  a[0] = cadd(E0, O0);  a[4] = csub(E0, O0);
  a[1] = cadd(E1, O1w); a[5] = csub(E1, O1w);
  a[2] = cadd(E2, O2w); a[6] = csub(E2, O2w);
  a[3] = cadd(E3, O3w); a[7] = csub(E3, O3w);
}

// 8-point inverse DFT (unnormalized, W8^{-1} = exp(+i*pi/4)), in place
__device__ __forceinline__ void dft8_inv(float2* a) {
  const float c = 0.70710678118654752f;
  float2 t0 = cadd(a[0], a[4]), t1 = csub(a[0], a[4]);
  float2 t2 = cadd(a[2], a[6]), t3 = csub(a[2], a[6]);
  float2 t4 = cadd(a[1], a[5]), t5 = csub(a[1], a[5]);
  float2 t6 = cadd(a[3], a[7]), t7 = csub(a[3], a[7]);
  float2 E0 = cadd(t0, t2), E2 = csub(t0, t2);
  float2 E1 = make_float2(t1.x - t3.y, t1.y + t3.x);   // t1 + i*t3
  float2 E3 = make_float2(t1.x + t3.y, t1.y - t3.x);   // t1 - i*t3
  float2 O0 = cadd(t4, t6), O2 = csub(t4, t6);
  float2 O1 = make_float2(t5.x - t7.y, t5.y + t7.x);
  float2 O3 = make_float2(t5.x + t7.y, t5.y - t7.x);
  float2 O1w = make_float2(c * (O1.x - O1.y), c * (O1.x + O1.y));   // *W8^-1
  float2 O2w = make_float2(-O2.y, O2.x);                            // *W8^-2=+i
  float2 O3w = make_float2(-c * (O3.x + O3.y), c * (O3.x - O3.y));  // *W8^-3
  a[0] = cadd(E0, O0);  a[4] = csub(E0, O0);
  a[1] = cadd(E1, O1w); a[5] = csub(E1, O1w);
  a[2] = cadd(E2, O2w); a[6] = csub(E2, O2w);
  a[3] = cadd(E3, O3w); a[7] = csub(E3, O3w);
}

// One radix-8 LDS stage (1024 butterflies over 8192 elems, 256 threads).
// Forward (DIF): DFT8 then twiddle W_{8d}^{j*k}. Inverse (DIT): conj-twiddle
// then IDFT8. Barrier at end.
template <bool INV>
__device__ __forceinline__ void stage8(float* zr, float* zi, const float2* __restrict__ tw,
                                       int tid, int d, int ld, int stride) {
  #pragma unroll
  for (int rep = 0; rep < 4; ++rep) {
    int idx = tid + rep * 256;
    int j = idx & (d - 1);
    int p = ((idx >> ld) << (ld + 3)) + j;
    float2 v[8];
    #pragma unroll
    for (int t = 0; t < 8; ++t) { int q = SWZ(p + t * d); v[t] = make_float2(zr[q], zi[q]); }
    if (INV) {
      #pragma unroll
      for (int k = 1; k < 8; ++k) v[k] = cmulc(v[k], tw[j * k * stride]);
      dft8_inv(v);
    } else {
      dft8_fwd(v);
      #pragma unroll
      for (int k = 1; k < 8; ++k) v[k] = cmul(v[k], tw[j * k * stride]);
    }
    #pragma unroll
    for (int t = 0; t < 8; ++t) { int q = SWZ(p + t * d); zr[q] = v[t].x; zi[q] = v[t].y; }
  }
  __syncthreads();
}

// 16-point FFT fully in registers (finishes the 8*8*8*16 factorization).
// Forward: radix-8 (d=2, n=16, stride=NFFT/16=512) then radix-2 (d=1).
__device__ __forceinline__ void reg16_fwd(float2* v, const float2* __restrict__ tw) {
  float2 t[8];
  #pragma unroll
  for (int k = 0; k < 8; ++k) t[k] = v[2 * k];     // j=0, twiddle=1
  dft8_fwd(t);
  #pragma unroll
  for (int k = 0; k < 8; ++k) v[2 * k] = t[k];
  #pragma unroll
  for (int k = 0; k < 8; ++k) t[k] = v[2 * k + 1]; // j=1
  dft8_fwd(t);
  #pragma unroll
  for (int k = 1; k < 8; ++k) t[k] = cmul(t[k], tw[k * 512]);
  #pragma unroll
  for (int k = 0; k < 8; ++k) v[2 * k + 1] = t[k];
  #pragma unroll
  for (int q = 0; q < 8; ++q) {
    float2 a = v[2 * q], b = v[2 * q + 1];
    v[2 * q] = cadd(a, b); v[2 * q + 1] = csub(a, b);
  }
}

__device__ __forceinline__ void reg16_inv(float2* v, const float2* __restrict__ tw) {
  #pragma unroll
  for (int q = 0; q < 8; ++q) {
    float2 a = v[2 * q], b = v[2 * q + 1];
    v[2 * q] = cadd(a, b); v[2 * q + 1] = csub(a, b);
  }
  float2 t[8];
  #pragma unroll
  for (int k = 0; k < 8; ++k) t[k] = v[2 * k];
  dft8_inv(t);
  #pragma unroll
  for (int k = 0; k < 8; ++k) v[2 * k] = t[k];
  #pragma unroll
  for (int k = 0; k < 8; ++k) t[k] = cmulc(v[2 * k + 1], tw[k * 512]);
  dft8_inv(t);
  #pragma unroll
  for (int k = 0; k < 8; ++k) v[2 * k + 1] = t[k];
}

// ---------------------------------------------------------------------------
// Masked MFN kernel generation. grid (K/256, 24); block y covers 16 channels.
// ---------------------------------------------------------------------------
__global__ __launch_bounds__(256) void gen_mk(
    const float* __restrict__ mask_mean, const float* __restrict__ mask_sigma,
    const float* __restrict__ gfw, const float* __restrict__ gfb,
    const float* __restrict__ gg,  const float* __restrict__ gmu,
    const float* __restrict__ lin_w, const float* __restrict__ lin_b,
    const float* __restrict__ out_w, const float* __restrict__ out_b,
    float* __restrict__ mk) {
  const int t = threadIdx.x;
  const int k = blockIdx.x * 256 + t;
  const int c0 = blockIdx.y * 16;
  const float xp = -1.0f + 2.0f * (float)k / (float)(K_ - 1);

  float h[KH_];
  #pragma unroll
  for (int j = 0; j < KH_; ++j) {
    float d   = gg[j] * (xp - gmu[j]);
    float env = expf(-0.5f * d * d);
    float su  = sinf(OMEGA_ * (xp * gfw[j]) + gfb[j]);
    h[j] = env * su;
  }
  for (int i = 0; i < NL_; ++i) {
    const float* lw = lin_w + i * KH_ * KH_;
    const int go = (i + 1) * KH_;
    float nh[KH_];
    #pragma unroll
    for (int h2 = 0; h2 < KH_; ++h2) {
      float acc = lin_b[i * KH_ + h2];
      #pragma unroll
      for (int j = 0; j < KH_; ++j) acc = fmaf(h[j], lw[h2 * KH_ + j], acc);
      float d   = gg[go + h2] * (xp - gmu[go + h2]);
      float env = expf(-0.5f * d * d);
      float su  = sinf(OMEGA_ * (xp * gfw[go + h2]) + gfb[go + h2]);
      nh[h2] = acc * (env * su);
    }
    #pragma unroll
    for (int j = 0; j < KH_; ++j) h[j] = nh[j];
  }
  float mw = (xp - mask_mean[0]) / mask_sigma[0];
  float ms = expf(-0.5f * mw * mw) * rsqrtf((float)(C_ * K_));
  #pragma unroll
  for (int j = 0; j < KH_; ++j) h[j] *= ms;

  for (int cc = 0; cc < 16; ++cc) {
    int c = c0 + cc;
    float acc = out_b[c] * ms;
    #pragma unroll
    for (int j = 0; j < KH_; ++j) acc = fmaf(h[j], out_w[c * KH_ + j], acc);
    mk[(size_t)c * K_ + k] = acc;
  }
}

// ---------------------------------------------------------------------------
// Kernel spectrum (scrambled mixed-radix order), scaled by 1/NFFT.
// ---------------------------------------------------------------------------
__global__ __launch_bounds__(256) void fft_h(const float* __restrict__ mk,
                                             const float2* __restrict__ tw,
                                             float2* __restrict__ Hspec) {
  extern __shared__ float smem[];
  float* zr = smem;
  float* zi = smem + NFFT;
  const int c = blockIdx.x;
  const int tid = threadIdx.x;
  const float4* row4 = reinterpret_cast<const float4*>(mk + (size_t)c * K_);
  const float4 z4 = make_float4(0.f, 0.f, 0.f, 0.f);
  for (int i = tid; i < K_ / 4; i += 256) {
    int p = i * 4;
    *reinterpret_cast<float4*>(&zr[SWZ(p)]) = row4[i];
    *reinterpret_cast<float4*>(&zi[SWZ(p)]) = z4;
    *reinterpret_cast<float4*>(&zr[SWZ(p + K_)]) = z4;
    *reinterpret_cast<float4*>(&zi[SWZ(p + K_)]) = z4;
  }
  __syncthreads();
  stage8<false>(zr, zi, tw, tid, 1024, 10, 1);
  stage8<false>(zr, zi, tw, tid, 128, 7, 8);
  stage8<false>(zr, zi, tw, tid, 16, 4, 64);

  const float inv = 1.0f / (float)NFFT;
  float2* outp = Hspec + (size_t)c * NFFT;
  #pragma unroll
  for (int rep = 0; rep < 2; ++rep) {
    int cb = tid + rep * 256;
    int base = cb * 16, pb = SWZ(base);
    float2 v[16];
    #pragma unroll
    for (int q4 = 0; q4 < 4; ++q4) {
      float4 re = *reinterpret_cast<const float4*>(&zr[pb + q4 * 4]);
      float4 im = *reinterpret_cast<const float4*>(&zi[pb + q4 * 4]);
      v[q4 * 4 + 0] = make_float2(re.x, im.x);
      v[q4 * 4 + 1] = make_float2(re.y, im.y);
      v[q4 * 4 + 2] = make_float2(re.z, im.z);
      v[q4 * 4 + 3] = make_float2(re.w, im.w);
    }
    reg16_fwd(v, tw);
    #pragma unroll
    for (int q = 0; q < 16; ++q) outp[base + q] = make_float2(v[q].x * inv, v[q].y * inv);
  }
}

// ---------------------------------------------------------------------------
// FFT convolution, two batches per block packed as real/imag.
// Forward 3 LDS stages + reg16 -> multiply H in regs -> inverse reg16 +
// 3 LDS stages. grid = (B/2)*C.
// ---------------------------------------------------------------------------
__global__ __launch_bounds__(256) void fft_conv(const float* __restrict__ x,
                                                const float2* __restrict__ Hspec,
                                                const float2* __restrict__ tw,
                                                float* __restrict__ y) {
  extern __shared__ float smem[];
  float* zr = smem;
  float* zi = smem + NFFT;
  const int c  = blockIdx.x % C_;
  const int pr = blockIdx.x / C_;
  const int b1 = 2 * pr, b2 = b1 + 1;
  const int tid = threadIdx.x;
  const float4* x1 = reinterpret_cast<const float4*>(x + ((size_t)b1 * C_ + c) * L_);
  const float4* x2 = reinterpret_cast<const float4*>(x + ((size_t)b2 * C_ + c) * L_);
  const float4 z4 = make_float4(0.f, 0.f, 0.f, 0.f);
  for (int i = tid; i < L_ / 4; i += 256) {
    int p = i * 4;
    *reinterpret_cast<float4*>(&zr[SWZ(p)]) = x1[i];
    *reinterpret_cast<float4*>(&zi[SWZ(p)]) = x2[i];
    *reinterpret_cast<float4*>(&zr[SWZ(p + L_)]) = z4;
    *reinterpret_cast<float4*>(&zi[SWZ(p + L_)]) = z4;
  }
  __syncthreads();
  stage8<false>(zr, zi, tw, tid, 1024, 10, 1);
  stage8<false>(zr, zi, tw, tid, 128, 7, 8);
  stage8<false>(zr, zi, tw, tid, 16, 4, 64);

  const float2* Hc = Hspec + (size_t)c * NFFT;
  #pragma unroll
  for (int rep = 0; rep < 2; ++rep) {
    int cb = tid + rep * 256;
    int base = cb * 16, pb = SWZ(base);
    float2 v[16];
    #pragma unroll
    for (int q4 = 0; q4 < 4; ++q4) {
      float4 re = *reinterpret_cast<const float4*>(&zr[pb + q4 * 4]);
      float4 im = *reinterpret_cast<const float4*>(&zi[pb + q4 * 4]);
      v[q4 * 4 + 0] = make_float2(re.x, im.x);
      v[q4 * 4 + 1] = make_float2(re.y, im.y);
      v[q4 * 4 + 2] = make_float2(re.z, im.z);
      v[q4 * 4 + 3] = make_float2(re.w, im.w);
    }
    reg16_fwd(v, tw);
    #pragma unroll
    for (int q = 0; q < 16; ++q) v[q] = cmul(v[q], Hc[base + q]);
    reg16_inv(v, tw);
    #pragma unroll
    for (int q4 = 0; q4 < 4; ++q4) {
      float4 re = make_float4(v[q4 * 4 + 0].x, v[q4 * 4 + 1].x, v[q4 * 4 + 2].x, v[q4 * 4 + 3].x);
      float4 im = make_float4(v[q4 * 4 + 0].y, v[q4 * 4 + 1].y, v[q4 * 4 + 2].y, v[q4 * 4 + 3].y);
      *reinterpret_cast<float4*>(&zr[pb + q4 * 4]) = re;
      *reinterpret_cast<float4*>(&zi[pb + q4 * 4]) = im;
    }
  }
  __syncthreads();
  stage8<true>(zr, zi, tw, tid, 16, 4, 64);
  stage8<true>(zr, zi, tw, tid, 128, 7, 8);
  stage8<true>(zr, zi, tw, tid, 1024, 10, 1);

  float4* y1 = reinterpret_cast<float4*>(y + ((size_t)b1 * C_ + c) * L_);
  float4* y2 = reinterpret_cast<float4*>(y + ((size_t)b2 * C_ + c) * L_);
  for (int i = tid; i < L_ / 4; i += 256) {
    int p = i * 4;
    y1[i] = *reinterpret_cast<const float4*>(&zr[SWZ(p)]);
    y2[i] = *reinterpret_cast<const float4*>(&zi[SWZ(p)]);
  }
}

// ---------------------------------------------------------------------------
// Pointwise 1x1 conv: out[b][o][l] = sum_c pw[o][c] * y[b][c][l]
// fp32 GEMM: 128x128 tile, BK=16, 256 threads, 2x2 blocks of 4x4 per thread.
// grid = (L/128, HID/128, B)
// ---------------------------------------------------------------------------
#define MT 128
#define NT 128
#define KT 16
#define LDT 132
__global__ __launch_bounds__(256) void pw_gemm(const float* __restrict__ y,
                                               const float* __restrict__ pw,
                                               float* __restrict__ out) {
  const int b  = blockIdx.z;
  const int m0 = blockIdx.y * MT;
  const int n0 = blockIdx.x * NT;
  __shared__ float As[KT][LDT];   // [k][m]
  __shared__ float Bs[KT][LDT];   // [k][n]
  const int tid = threadIdx.x;
  const int tx = tid & 15, ty = tid >> 4;
  float acc[2][2][4][4] = {{{{0.f}}}};
  const float* yb = y + (size_t)b * C_ * L_;

  for (int k0 = 0; k0 < C_; k0 += KT) {
    #pragma unroll
    for (int rep = 0; rep < 2; ++rep) {  // A tile: pw[m0+row][k0+c4..], transpose
      int idx = tid + rep * 256;
      int row = idx >> 2, c4 = (idx & 3) << 2;
      float4 av = *reinterpret_cast<const float4*>(pw + (size_t)(m0 + row) * C_ + k0 + c4);
      As[c4 + 0][row] = av.x; As[c4 + 1][row] = av.y;
      As[c4 + 2][row] = av.z; As[c4 + 3][row] = av.w;
    }
    #pragma unroll
    for (int rep = 0; rep < 2; ++rep) {  // B tile: y[b][k0+r][n0+cc..]
      int idx = tid + rep * 256;
      int r = idx >> 5, cc = (idx & 31) << 2;
      float4 bv = *reinterpret_cast<const float4*>(yb + (size_t)(k0 + r) * L_ + n0 + cc);
      *reinterpret_cast<float4*>(&Bs[r][cc]) = bv;
    }
    __syncthreads();
    #pragma unroll
    for (int kk = 0; kk < KT; ++kk) {
      float4 a0 = *reinterpret_cast<const float4*>(&As[kk][ty * 4]);
      float4 a1 = *reinterpret_cast<const float4*>(&As[kk][ty * 4 + 64]);
      float4 b0 = *reinterpret_cast<const float4*>(&Bs[kk][tx * 4]);
      float4 b1 = *reinterpret_cast<const float4*>(&Bs[kk][tx * 4 + 64]);
      float av[2][4] = {{a0.x, a0.y, a0.z, a0.w}, {a1.x, a1.y, a1.z, a1.w}};
      float bv[2][4] = {{b0.x, b0.y, b0.z, b0.w}, {b1.x, b1.y, b1.z, b1.w}};
      #pragma unroll
      for (int ri = 0; ri < 2; ++ri)
        #pragma unroll
        for (int rj = 0; rj < 2; ++rj)
          #pragma unroll
          for (int i = 0; i < 4; ++i)
            #pragma unroll
            for (int j = 0; j < 4; ++j)
              acc[ri][rj][i][j] = fmaf(av[ri][i], bv[rj][j], acc[ri][rj][i][j]);
    }
    __syncthreads();
  }
  #pragma unroll
  for (int ri = 0; ri < 2; ++ri)
    #pragma unroll
    for (int i = 0; i < 4; ++i) {
      int grow = m0 + ty * 4 + i + ri * 64;
      float* orow = out + ((size_t)b * HID_ + grow) * L_ + n0;
      #pragma unroll
      for (int rj = 0; rj < 2; ++rj) {
        float4 v = make_float4(acc[ri][rj][i][0], acc[ri][rj][i][1],
                               acc[ri][rj][i][2], acc[ri][rj][i][3]);
        *reinterpret_cast<float4*>(orow + tx * 4 + rj * 64) = v;
      }
    }
}

// ---------------------------------------------------------------------------
extern "C" void kernel_launch(void* const* d_in, const int* in_sizes, int n_in,
                              void* d_out, int out_size, void* d_ws, size_t ws_size,
                              hipStream_t stream) {
  (void)in_sizes; (void)n_in; (void)out_size; (void)ws_size;
  const float* x          = (const float*)d_in[0];
  const float* mask_mean  = (const float*)d_in[1];
  const float* mask_sigma = (const float*)d_in[2];
  const float* gfw        = (const float*)d_in[3];
  const float* gfb        = (const float*)d_in[4];
  const float* gg         = (const float*)d_in[5];
  const float* gmu        = (const float*)d_in[6];
  const float* lin_w      = (const float*)d_in[7];
  const float* lin_b      = (const float*)d_in[8];
  const float* out_w      = (const float*)d_in[9];
  const float* out_b      = (const float*)d_in[10];
  const float* pw_w       = (const float*)d_in[11];
  float* out = (float*)d_out;

  // workspace layout (16B-aligned):
  //   tw    : float2[NFFT]          65536 B
  //   mk    : float [C*K]         6291456 B
  //   Hspec : float2[C*NFFT]     25165824 B
  //   y     : float [B*C*L]     100663296 B   (total ~132.3 MB)
  char* ws = (char*)d_ws;
  float2* tw = (float2*)ws;
  float*  mk = (float*)(ws + 65536);
  float2* Hs = (float2*)(ws + 65536 + 6291456);
  float*  y  = (float*)(ws + 65536 + 6291456 + 25165824);

  gen_tw<<<NFFT / 256, 256, 0, stream>>>(tw);
  gen_mk<<<dim3(K_ / 256, 24), 256, 0, stream>>>(mask_mean, mask_sigma, gfw, gfb, gg, gmu,
                                                 lin_w, lin_b, out_w, out_b, mk);
  fft_h<<<C_, 256, 2 * NFFT * sizeof(float), stream>>>(mk, tw, Hs);
  fft_conv<<<(B_ / 2) * C_, 256, 2 * NFFT * sizeof(float), stream>>>(x, Hs, tw, y);
  pw_gemm<<<dim3(L_ / NT, HID_ / MT, B_), 256, 0, stream>>>(y, pw_w, out);
}